// Round 10
// baseline (2843.164 us; speedup 1.0000x reference)
//
#include <hip/hip_runtime.h>
#include <math.h>

// CRITICAL: no FMA contraction anywhere — we are bit-replicating numpy's
// SSE (no-FMA) float32 einsum inner loop.
#pragma clang fp contract(off)

#define T_TOKENS 16384
#define HDIM 2048
#define NEXP 64
#define TOPK 6
#define SEQ 4096
#define TPB 32          // tokens per block
#define KC 64           // k-chunk (floats) = 16 float4 slots
#define NC (HDIM / KC)  // 32 chunks
#define LGS 65          // padded stride for logits
#define PS 65           // padded stride for probs

typedef __attribute__((address_space(1))) const unsigned int gu32;
typedef __attribute__((address_space(3))) unsigned int lu32;

// numpy einsum contig_two micro-step (SSE3 baseline, 4 lanes, no FMA):
// per 16-element block: vacc[l] = a0[l]*b0[l] + (a1[l]*b1[l] + (a2[l]*b2[l] + (a3[l]*b3[l] + vacc[l])))
__device__ __forceinline__ void np_upd(const float4& w0, const float4& w1,
                                       const float4& w2, const float4& w3,
                                       const float4& x0, const float4& x1,
                                       const float4& x2, const float4& x3,
                                       float acc[4])
{
    acc[0] = w0.x*x0.x + (w1.x*x1.x + (w2.x*x2.x + (w3.x*x3.x + acc[0])));
    acc[1] = w0.y*x0.y + (w1.y*x1.y + (w2.y*x2.y + (w3.y*x3.y + acc[1])));
    acc[2] = w0.z*x0.z + (w1.z*x1.z + (w2.z*x2.z + (w3.z*x3.z + acc[2])));
    acc[3] = w0.w*x0.w + (w1.w*x1.w + (w2.w*x2.w + (w3.w*x3.w + acc[3])));
}

// 512 threads = 8 waves; thread = 1 token x 4 experts (R2-proven mapping).
// Async staging via global_load_lds (zero reg residency), double-buffered,
// ONE barrier per chunk. Conflict-free LDS layouts with ALL read addresses
// = loop-invariant register + compile-time immediate:
//   W transposed [slot][expert]: byte = s*1024 + e*16  (1 addr reg: le*16)
//   X rotated-in-4-groups: phys slot = (s&~3)|((s+row)&3)  (4 addr regs)
__global__ __launch_bounds__(512, 4) void moe_gate_main(
    const float* __restrict__ x, const float* __restrict__ wgt,
    float* __restrict__ out, float* __restrict__ gacc)
{
    __shared__ __attribute__((aligned(16))) float w_lds[2 * NEXP * KC];  // 32 KB, transposed
    __shared__ __attribute__((aligned(16))) float x_lds[2 * TPB * KC];   // 16 KB, rotated
    __shared__ float lg[TPB * LGS];        //  8320 B fp32 logits (np bit-exact)
    __shared__ float probs[TPB * PS];      //  8320 B
    __shared__ float psum[8 * NEXP];       //  2048 B
    __shared__ int   cnt[NEXP];            //   256 B   (~68 KB total, 2 blocks/CU)

    const int tid  = threadIdx.x;
    const int bid  = blockIdx.x;
    const int tb   = bid * TPB;
    const int b    = tb / SEQ;

    const int lane = tid & 63;
    const int wv   = tid >> 6;       // 0..7
    const int le   = lane & 15;      // expert sub-index: experts le+16*je
    const int g    = lane >> 4;      // 0..3
    const int trow = wv * 4 + g;     // token row 0..31

    // ---- staging geometry (all loop-invariant) ----
    // W transposed: unit u = s*64 + e  (s in [0,16), e in [0,64)).
    // Round A: units 0..511 (s=tid>>6), round B: units 512..1023 (s=8+(tid>>6)).
    const int we = tid & 63;
    const int ws = tid >> 6;
    const float* wsA = wgt + (size_t)we * HDIM + ws * 4;
    const float* wsB = wsA + 32;                       // slots 8..15
    // X rotated: unit u = t*16 + sp; phys sp holds logical (sp&~3)|((sp-t)&3)
    const int xt  = tid >> 4;
    const int xsp = tid & 15;
    const int xsl = (xsp & ~3) | ((xsp - xt) & 3);
    const float* xsrc = x + (size_t)(tb + xt) * HDIM + xsl * 4;
    // LDS linear dests (wave-uniform base + lane*16, m97-verified form)
    char* wdA = (char*)w_lds + tid * 16;
    char* wdB = wdA + 8192;
    char* xd  = (char*)x_lds + tid * 16;

    // ---- read addressing: 1 W reg + 4 X regs, rest immediates ----
    const char* wbp = (const char*)w_lds + le * 16;
    const char* xad0 = (const char*)x_lds + trow * 256 + (((0 + trow) & 3) << 4);
    const char* xad1 = (const char*)x_lds + trow * 256 + (((1 + trow) & 3) << 4);
    const char* xad2 = (const char*)x_lds + trow * 256 + (((2 + trow) & 3) << 4);
    const char* xad3 = (const char*)x_lds + trow * 256 + (((3 + trow) & 3) << 4);

    float acc[4][4];
    #pragma unroll
    for (int j = 0; j < 4; ++j)
        #pragma unroll
        for (int l = 0; l < 4; ++l) acc[j][l] = 0.f;

#define GLL(SRC, DST) __builtin_amdgcn_global_load_lds((gu32*)(SRC), (lu32*)(DST), 16, 0, 0)

    // COMPUTE(BW, BX): consume buffer at byte offsets BW (W) / BX (X).
    // k ascending in blocks of 16 (matches numpy's loop order); per b16,
    // per je: w_j at  BW + b16*4096 + j*1024 + je*256  (W transposed),
    //         xa_j at BX + b16*64 from xad_j (rotation folded into xad_j).
#define COMPUTE(BW, BX)                                                        \
    {                                                                          \
        _Pragma("unroll")                                                      \
        for (int b16 = 0; b16 < 4; ++b16) {                                    \
            const float4 xa0 = *(const float4*)(xad0 + (BX) + b16 * 64);       \
            const float4 xa1 = *(const float4*)(xad1 + (BX) + b16 * 64);       \
            const float4 xa2 = *(const float4*)(xad2 + (BX) + b16 * 64);       \
            const float4 xa3 = *(const float4*)(xad3 + (BX) + b16 * 64);       \
            _Pragma("unroll")                                                  \
            for (int je = 0; je < 4; ++je) {                                   \
                const char* wp = wbp + (BW) + b16 * 4096 + je * 256;           \
                const float4 w0 = *(const float4*)(wp);                        \
                const float4 w1 = *(const float4*)(wp + 1024);                 \
                const float4 w2 = *(const float4*)(wp + 2048);                 \
                const float4 w3 = *(const float4*)(wp + 3072);                 \
                np_upd(w0, w1, w2, w3, xa0, xa1, xa2, xa3, acc[je]);           \
            }                                                                  \
        }                                                                      \
    }

    // ---- prologue: stage chunk 0 into buffer 0 (async, reg-free)
    GLL(wsA, wdA); GLL(wsB, wdB); GLL(xsrc, xd);
    wsA += KC; wsB += KC; xsrc += KC;
    __syncthreads();                    // compiler drains vmcnt before barrier

    #pragma unroll 1
    for (int cc = 0; cc < NC / 2; ++cc) {
        // stage odd chunk (2cc+1) -> buf1; in flight under compute of 2cc
        GLL(wsA, wdA + 16384); GLL(wsB, wdB + 16384); GLL(xsrc, xd + 8192);
        wsA += KC; wsB += KC; xsrc += KC;
        COMPUTE(0, 0)
        __syncthreads();
        // stage even chunk (2cc+2) -> buf0; in flight under compute of 2cc+1
        if (cc + 1 < NC / 2) {
            GLL(wsA, wdA); GLL(wsB, wdB); GLL(xsrc, xd);
            wsA += KC; wsB += KC; xsrc += KC;
        }
        COMPUTE(16384, 8192)
        __syncthreads();
    }
#undef COMPUTE
#undef GLL

    // horizontal reduce exactly like npyv_sum_f32 (SSE3 hadd): (v0+v1)+(v2+v3)
    #pragma unroll
    for (int je = 0; je < 4; ++je) {
        float v = (acc[je][0] + acc[je][1]) + (acc[je][2] + acc[je][3]);
        lg[trow * LGS + le + 16 * je] = v;
    }
    if (tid < NEXP) cnt[tid] = 0;
    __syncthreads();

    // ---- softmax per token (threads 0..31), fp32 like np
    if (tid < TPB) {
        const int t = tid;
        float mx = lg[t * LGS];
        for (int e = 1; e < NEXP; ++e) { float v = lg[t * LGS + e]; if (v > mx) mx = v; }
        for (int e = 0; e < NEXP; ++e)
            probs[t * PS + e] = expf(lg[t * LGS + e] - mx);
        // numpy pairwise sum, n=64: 8 strided accumulators then paired combine
        float r[8];
        #pragma unroll
        for (int j = 0; j < 8; ++j) r[j] = probs[t * PS + j];
        for (int i = 8; i < 64; i += 8)
            #pragma unroll
            for (int j = 0; j < 8; ++j) r[j] += probs[t * PS + i + j];
        float S = ((r[0] + r[1]) + (r[2] + r[3])) + ((r[4] + r[5]) + (r[6] + r[7]));
        for (int e = 0; e < NEXP; ++e) probs[t * PS + e] = probs[t * PS + e] / S;
    }
    __syncthreads();

    // ---- partial per-expert score sums (aux loss), all 512 threads
    {
        const int e = tid & 63, q = tid >> 6;   // q = 0..7, 4 tokens each
        float s = 0.f;
        for (int t = q * 4; t < q * 4 + 4; ++t) s += probs[t * PS + e];
        psum[q * 64 + e] = s;
    }
    __syncthreads();

    if (tid < TPB) {
        // ---- top-6 on fp32 probs, strict > ascending scan (tie -> lowest index)
        const int t = tid;
        const int gt = tb + t;
        float pv[TOPK]; int pi[TOPK];
        for (int r = 0; r < TOPK; ++r) {
            float bv = -1.f; int be = 0;
            for (int e = 0; e < NEXP; ++e) {
                float v = probs[t * PS + e];
                if (v > bv) { bv = v; be = e; }
            }
            probs[t * PS + be] = -1.f;
            pv[r] = bv; pi[r] = be;
            atomicAdd(&cnt[be], 1);
        }
        float wsum = pv[0];
        #pragma unroll
        for (int r = 1; r < TOPK; ++r) wsum += pv[r];
        wsum += 1e-20f;
        #pragma unroll
        for (int r = 0; r < TOPK; ++r) {
            out[(size_t)gt * TOPK + r] = (float)pi[r];
            out[(size_t)T_TOKENS * TOPK + (size_t)gt * TOPK + r] = pv[r] / wsum;
        }
    } else if (tid >= 64 && tid < 128) {
        const int e = tid - 64;
        float s = 0.f;
        #pragma unroll
        for (int q = 0; q < 8; ++q) s += psum[q * 64 + e];
        atomicAdd(&gacc[b * 64 + e], s);
    }
    __syncthreads();
    if (tid < NEXP) {
        atomicAdd(&gacc[256 + b * 64 + tid], (float)cnt[tid]);
    }
}

__global__ __launch_bounds__(256) void moe_gate_aux(
    const float* __restrict__ gacc, float* __restrict__ out)
{
    __shared__ float red[4];
    const int tid = threadIdx.x;
    float v = gacc[256 + tid] * gacc[tid];
    #pragma unroll
    for (int o = 32; o > 0; o >>= 1) v += __shfl_down(v, o, 64);
    if ((tid & 63) == 0) red[tid >> 6] = v;
    __syncthreads();
    if (tid == 0) {
        float tot = red[0] + red[1] + red[2] + red[3];
        const float scale = (64.0f / (4096.0f * 6.0f)) / 4096.0f;
        out[2 * T_TOKENS * TOPK] = 1e-3f * (tot * scale) * 0.25f;
    }
}

extern "C" void kernel_launch(void* const* d_in, const int* in_sizes, int n_in,
                              void* d_out, int out_size, void* d_ws, size_t ws_size,
                              hipStream_t stream) {
    const float* x   = (const float*)d_in[0];
    const float* wgt = (const float*)d_in[1];
    float* out  = (float*)d_out;
    float* gacc = (float*)d_ws;

    hipMemsetAsync(d_ws, 0, 512 * sizeof(float), stream);
    moe_gate_main<<<T_TOKENS / TPB, 512, 0, stream>>>(x, wgt, out, gacc);
    moe_gate_aux<<<1, 256, 0, stream>>>(gacc, out);
}